// Round 2
// baseline (3041.332 us; speedup 1.0000x reference)
//
#include <hip/hip_runtime.h>
#include <hip/hip_bf16.h>

typedef __attribute__((ext_vector_type(8))) short short8;
typedef __attribute__((ext_vector_type(8))) __bf16 bf16x8;
typedef __attribute__((ext_vector_type(4))) float f32x4;

#define NNODES 30000
#define NT 16          // nodes per workgroup
#define NSLOT 18

__device__ __forceinline__ short bf16s(float f) {
    return __builtin_bit_cast(short, __float2bfloat16(f));
}

__device__ __forceinline__ f32x4 mfma_bf16(short8 a, short8 b, f32x4 c) {
    return __builtin_amdgcn_mfma_f32_16x16x32_bf16(
        __builtin_bit_cast(bf16x8, a), __builtin_bit_cast(bf16x8, b), c, 0, 0, 0);
}

// ---- kernel 0: convert 6 weights (256x256 fp32, row = out j, col = in d) to bf16
// fragment-linear layout: WB[w][d>>3][j][d&7]  (elem off = w*65536 + (d>>3)*2048 + j*8 + (d&7))
__global__ void wconv(const float* __restrict__ Ws, const float* __restrict__ Wp,
                      const float* __restrict__ Wk, const float* __restrict__ Wq,
                      const float* __restrict__ Wv, const float* __restrict__ Wf,
                      short* __restrict__ out) {
    int idx = blockIdx.x * 256 + threadIdx.x;      // 0 .. 6*65536-1
    int w = idx >> 16, e = idx & 65535;
    const float* src = w == 0 ? Ws : w == 1 ? Wp : w == 2 ? Wk : w == 3 ? Wq : w == 4 ? Wv : Wf;
    int b = e & 7, j = (e >> 3) & 255, dc = e >> 11;
    int d = dc * 8 + b;
    out[idx] = bf16s(src[j * 256 + d]);
}

// ---- fused kernel: 16 nodes per workgroup, 4 waves
__global__ __launch_bounds__(256, 2) void chienn_fused(
    const float* __restrict__ x, const int* __restrict__ pidx,
    const float* __restrict__ ccw, const int* __restrict__ ccw_mask,
    const float* __restrict__ cw, const int* __restrict__ cw_mask,
    const short* __restrict__ WB, float* __restrict__ out) {

    const int tid  = threadIdx.x;
    const int wid  = tid >> 6;
    const int lane = tid & 63;
    const int l4   = lane & 15;
    const int lhi  = lane >> 4;
    const int n0   = blockIdx.x * NT;
    const int g    = n0 + l4;          // this lane's node (A-fragment row)

    __shared__ short lds_msgsp[2 * 16 * 256];   // self/par rows, bf16, XOR-swizzled
    __shared__ float lds_k[16 * 264];           // k vectors fp32, padded
    __shared__ float lds_score[16 * 8 * 20];    // scores -> p_attn
    __shared__ float lds_out[16 * 260];         // attn output accum fp32, padded

    // B fragment: weight widx, k-step kk, N-tile jt
    auto bfrag = [&](int widx, int kk, int jt) -> short8 {
        return *(const short8*)(WB + ((widx * 32 + kk * 4 + lhi) * 2048) + (jt * 16 + l4) * 8);
    };
    // A fragment from a global fp32 row (row = this lane's node)
    auto afrag_g = [&](const float* rowp, int kk) -> short8 {
        const float* p = rowp + kk * 32 + lhi * 8;
        f32x4 a0 = *(const f32x4*)p;
        f32x4 a1 = *(const f32x4*)(p + 4);
        short8 v;
        v[0] = bf16s(a0[0]); v[1] = bf16s(a0[1]); v[2] = bf16s(a0[2]); v[3] = bf16s(a0[3]);
        v[4] = bf16s(a1[0]); v[5] = bf16s(a1[1]); v[6] = bf16s(a1[2]); v[7] = bf16s(a1[3]);
        return v;
    };
    // A fragment from lds_msgsp (sp=0 self, 1 parallel), swizzled
    auto afrag_sp = [&](int sp, int kk) -> short8 {
        int d0 = kk * 32 + lhi * 8;
        return *(const short8*)(lds_msgsp + ((sp * 16 + l4) << 8) + (d0 ^ ((l4 & 7) << 3)));
    };

    // ================= Stage 1: self / parallel / k matvecs =================
    if (wid < 3) {
        f32x4 acc[16];
#pragma unroll
        for (int jt = 0; jt < 16; jt++) acc[jt] = (f32x4){0.f, 0.f, 0.f, 0.f};
        const float* rowp;
        if (wid == 0)      rowp = x + (size_t)g * 256;
        else if (wid == 1) rowp = x + (size_t)pidx[g] * 256;
        else               rowp = ccw + (size_t)g * 2048;   // slot 0 row
        for (int kk = 0; kk < 8; kk++) {
            short8 av = afrag_g(rowp, kk);
#pragma unroll
            for (int jt = 0; jt < 16; jt++)
                acc[jt] = mfma_bf16(av, bfrag(wid, kk, jt), acc[jt]);
        }
        if (wid < 2) {
#pragma unroll
            for (int jt = 0; jt < 16; jt++)
#pragma unroll
                for (int r = 0; r < 4; r++) {
                    int node = lhi * 4 + r, j = jt * 16 + l4;
                    lds_msgsp[((wid * 16 + node) << 8) + (j ^ ((node & 7) << 3))] = bf16s(acc[jt][r]);
                }
        } else {
#pragma unroll
            for (int jt = 0; jt < 16; jt++)
#pragma unroll
                for (int r = 0; r < 4; r++) {
                    int node = lhi * 4 + r, j = jt * 16 + l4;
                    lds_k[node * 264 + j] = acc[jt][r];
                }
        }
    }
    __syncthreads();

    // ================= Stage 2a: q GEMM per slot, scores fused in epilogue =================
    for (int s = wid; s < NSLOT; s += 4) {
        f32x4 acc[16];
#pragma unroll
        for (int jt = 0; jt < 16; jt++) acc[jt] = (f32x4){0.f, 0.f, 0.f, 0.f};
        const float* rowp = nullptr;
        int sp = -1;
        if (s < 8)       rowp = ccw + (size_t)g * 2048 + s * 256;
        else if (s == 8) sp = 0;
        else if (s == 9) sp = 1;
        else             rowp = cw + (size_t)g * 2048 + (s - 10) * 256;
        for (int kk = 0; kk < 8; kk++) {
            short8 av = (sp >= 0) ? afrag_sp(sp, kk) : afrag_g(rowp, kk);
#pragma unroll
            for (int jt = 0; jt < 16; jt++)
                acc[jt] = mfma_bf16(av, bfrag(3, kk, jt), acc[jt]);
        }
        const float scale = 0.17677669529663687f;  // 1/sqrt(32)
#pragma unroll
        for (int h = 0; h < 8; h++) {
            float part[4] = {0.f, 0.f, 0.f, 0.f};
#pragma unroll
            for (int jj = 0; jj < 2; jj++) {
                int jt = h * 2 + jj;
#pragma unroll
                for (int r = 0; r < 4; r++) {
                    int node = lhi * 4 + r;
                    part[r] += acc[jt][r] * lds_k[node * 264 + jt * 16 + l4];
                }
            }
#pragma unroll
            for (int r = 0; r < 4; r++) {
                float v = part[r];
                v += __shfl_xor(v, 1); v += __shfl_xor(v, 2);
                v += __shfl_xor(v, 4); v += __shfl_xor(v, 8);
                if (l4 == 0) lds_score[((lhi * 4 + r) * 8 + h) * 20 + s] = v * scale;
            }
        }
    }
    __syncthreads();

    // ================= softmax over 18 slots (one thread per node,head) =================
    for (int i = tid; i < 16 * 260; i += 256) lds_out[i] = 0.f;
    if (tid < 128) {
        int node = tid >> 3, h = tid & 7;
        int gn = n0 + node;
        float sc[NSLOT]; bool valid[NSLOT];
        float m = -1e30f;
#pragma unroll
        for (int s = 0; s < NSLOT; s++) {
            bool val;
            if (s < 8)       val = ccw_mask[gn * 8 + s] != 0;
            else if (s < 10) val = true;
            else             val = cw_mask[gn * 8 + (s - 10)] != 0;
            valid[s] = val;
            float v = lds_score[(node * 8 + h) * 20 + s];
            sc[s] = v;
            if (val && v > m) m = v;
        }
        float den = 0.f;
#pragma unroll
        for (int s = 0; s < NSLOT; s++) {
            float e = valid[s] ? __expf(sc[s] - m) : 0.f;
            sc[s] = e; den += e;
        }
        float inv = 1.f / den;
#pragma unroll
        for (int s = 0; s < NSLOT; s++) lds_score[(node * 8 + h) * 20 + s] = sc[s] * inv;
    }
    __syncthreads();

    // ================= Stage 2b: v GEMM per slot, PV fused (register accum) =================
    {
        f32x4 oacc[16];
#pragma unroll
        for (int jt = 0; jt < 16; jt++) oacc[jt] = (f32x4){0.f, 0.f, 0.f, 0.f};
        for (int s = wid; s < NSLOT; s += 4) {
            f32x4 vacc[16];
#pragma unroll
            for (int jt = 0; jt < 16; jt++) vacc[jt] = (f32x4){0.f, 0.f, 0.f, 0.f};
            const float* rowp = nullptr;
            int sp = -1;
            if (s < 8)       rowp = ccw + (size_t)g * 2048 + s * 256;
            else if (s == 8) sp = 0;
            else if (s == 9) sp = 1;
            else             rowp = cw + (size_t)g * 2048 + (s - 10) * 256;
            for (int kk = 0; kk < 8; kk++) {
                short8 av = (sp >= 0) ? afrag_sp(sp, kk) : afrag_g(rowp, kk);
#pragma unroll
                for (int jt = 0; jt < 16; jt++)
                    vacc[jt] = mfma_bf16(av, bfrag(4, kk, jt), vacc[jt]);
            }
#pragma unroll
            for (int jt = 0; jt < 16; jt++) {
                int h = jt >> 1;
#pragma unroll
                for (int r = 0; r < 4; r++) {
                    int node = lhi * 4 + r;
                    float p = lds_score[(node * 8 + h) * 20 + s];
                    oacc[jt][r] += p * vacc[jt][r];
                }
            }
        }
#pragma unroll
        for (int jt = 0; jt < 16; jt++)
#pragma unroll
            for (int r = 0; r < 4; r++) {
                int node = lhi * 4 + r;
                atomicAdd(&lds_out[node * 260 + jt * 16 + l4], oacc[jt][r]);
            }
    }
    __syncthreads();

    // ================= final: out = attn(16x256) @ Wf^T =================
    {
        f32x4 facc[4];
#pragma unroll
        for (int q = 0; q < 4; q++) facc[q] = (f32x4){0.f, 0.f, 0.f, 0.f};
        for (int kk = 0; kk < 8; kk++) {
            int d0 = kk * 32 + lhi * 8;
            const float* p = lds_out + l4 * 260 + d0;
            f32x4 a0 = *(const f32x4*)p;
            f32x4 a1 = *(const f32x4*)(p + 4);
            short8 av;
            av[0] = bf16s(a0[0]); av[1] = bf16s(a0[1]); av[2] = bf16s(a0[2]); av[3] = bf16s(a0[3]);
            av[4] = bf16s(a1[0]); av[5] = bf16s(a1[1]); av[6] = bf16s(a1[2]); av[7] = bf16s(a1[3]);
#pragma unroll
            for (int q = 0; q < 4; q++)
                facc[q] = mfma_bf16(av, bfrag(5, kk, wid * 4 + q), facc[q]);
        }
#pragma unroll
        for (int q = 0; q < 4; q++) {
            int jt = wid * 4 + q;
#pragma unroll
            for (int r = 0; r < 4; r++) {
                int node = lhi * 4 + r;
                out[(size_t)(n0 + node) * 256 + jt * 16 + l4] = facc[q][r];
            }
        }
    }
}

extern "C" void kernel_launch(void* const* d_in, const int* in_sizes, int n_in,
                              void* d_out, int out_size, void* d_ws, size_t ws_size,
                              hipStream_t stream) {
    (void)in_sizes; (void)n_in; (void)out_size; (void)ws_size;
    const float* x        = (const float*)d_in[0];
    const int*   pidx     = (const int*)d_in[1];
    const float* ccw      = (const float*)d_in[2];
    const int*   ccw_mask = (const int*)d_in[3];
    const float* cw       = (const float*)d_in[4];
    const int*   cw_mask  = (const int*)d_in[5];
    const float* Wself    = (const float*)d_in[6];
    const float* Wpar     = (const float*)d_in[7];
    const float* Wq       = (const float*)d_in[8];
    const float* Wk       = (const float*)d_in[9];
    const float* Wv       = (const float*)d_in[10];
    const float* Wf       = (const float*)d_in[11];
    short* WB = (short*)d_ws;   // 6 * 65536 bf16 = 768 KB

    wconv<<<dim3(6 * 65536 / 256), dim3(256), 0, stream>>>(Wself, Wpar, Wk, Wq, Wv, Wf, WB);
    chienn_fused<<<dim3(NNODES / NT), dim3(256), 0, stream>>>(
        x, pidx, ccw, ccw_mask, cw, cw_mask, WB, (float*)d_out);
}